// Round 11
// baseline (944.105 us; speedup 1.0000x reference)
//
#include <hip/hip_runtime.h>
#include <hip/hip_fp16.h>

#define NUSERS 100000
#define NGAMES 50000
#define NEDGES 1000000
#define NT     300000   // concatenated dst-counter space: 2*NGAMES + 2*NUSERS
#define NT4    75000    // NT/4
#define SCAN_B 293      // ceil(NT4/256)
#define TUB    3125     // ceil(NUSERS/32) transform user blocks
#define TGB    1563     // ceil(NGAMES/32) transform game blocks
#define HB     3907     // ceil(NEDGES/256) hist blocks per relation
// C=64, H=8, D=8, NEG_SLOPE=0.2

// One logical relation: key = node id the segment is grouped by,
// payload = node id stored into the segment. base = counter-space offset.
struct KRel { const int* key; const int* payload; int base; unsigned short* rank; };
struct K4 { KRel r[4]; };
struct AggRel { const float* als; const float* ald; const __half* hsrc;
                float* outp; int base; int n_dst; };
struct ARels { AggRel r[4]; };
struct SemP { const float* p[4]; int n[4]; };
struct TParm { const float* x; const float* W; const float* b;
               const float* att0; const float* att1; const float* att2; const float* att3;
               __half* hout; float* al0; float* al1; float* al2; float* al3; int N; };
struct T2 { TParm t[2]; };

// K1 (fused): grid-sliced kernel.
//  blocks [0, TUB+TGB): transform — h = x@W^T + b (fp16 out) + attention logits.
//  blocks [TUB+TGB, +4*HB): hist_rank — degree histogram whose atomicAdd return
//  value IS the edge's rank (stored coalesced, 2B/edge).
//  Transform is VALU/LDS-heavy, hist is transaction-bound with idle VALU —
//  fusing them lets transform ride along ~free.
__global__ __launch_bounds__(256) void trans_hist_kernel(T2 TP, K4 KP,
                                                         int* __restrict__ deg) {
  int bid = blockIdx.x;
  if (bid < TUB + TGB) {
    TParm R = (bid < TUB) ? TP.t[0] : TP.t[1];
    int nb = (bid < TUB ? bid : bid - TUB) * 32;
    if (nb >= R.N) return;
    __shared__ float Wl[64][65];   // +1 pad: lanes read Wl[c][k] conflict-free
    __shared__ float xl[4][64];
    int tid = threadIdx.x;
    for (int i = tid; i < 4096; i += 256) Wl[i>>6][i&63] = R.W[i];
    int nl = tid>>6, c = tid&63;
    float bc  = R.b[c];
    float a0c = R.att0[c], a1c = R.att1[c], a2c = R.att2[c], a3c = R.att3[c];
    for (int pass = 0; pass < 8; ++pass) {
      int n = nb + pass*4 + nl;
      __syncthreads();                       // xl reuse guard (covers W load on pass 0)
      if (n < R.N) xl[nl][c] = R.x[(size_t)n*64 + c];
      __syncthreads();
      if (n >= R.N) continue;                // no syncs below — safe divergence
      float acc = bc;
      #pragma unroll
      for (int k = 0; k < 64; ++k) acc += xl[nl][k]*Wl[c][k];
      R.hout[(size_t)n*64+c] = __float2half(acc);
      float p0 = acc*a0c, p1 = acc*a1c, p2 = acc*a2c, p3 = acc*a3c;
      #pragma unroll
      for (int mask = 1; mask < 8; mask <<= 1) {  // reduce over d in each head's 8 lanes
        p0 += __shfl_xor(p0, mask);
        p1 += __shfl_xor(p1, mask);
        p2 += __shfl_xor(p2, mask);
        p3 += __shfl_xor(p3, mask);
      }
      int d = c&7, hh = c>>3;
      if      (d == 0) R.al0[n*8+hh] = p0;
      else if (d == 1) R.al1[n*8+hh] = p1;
      else if (d == 2) R.al2[n*8+hh] = p2;
      else if (d == 3) R.al3[n*8+hh] = p3;
    }
  } else {
    int hb  = bid - (TUB + TGB);
    int rel = hb / HB;
    int eb  = hb - rel*HB;
    KRel R = KP.r[rel];
    int e = eb*256 + threadIdx.x;
    if (e >= NEDGES) return;
    R.rank[e] = (unsigned short)atomicAdd(&deg[R.base + R.key[e]], 1);
  }
}

// K3a: per-block (1024-elem) sums
__global__ __launch_bounds__(256) void scan_blocksum(const int* __restrict__ deg,
                                                     int* __restrict__ bsum) {
  __shared__ int red[256];
  int t = threadIdx.x;
  int i4 = blockIdx.x*256 + t;
  int4 v = (i4 < NT4) ? ((const int4*)deg)[i4] : int4{0,0,0,0};
  red[t] = v.x+v.y+v.z+v.w;
  __syncthreads();
  for (int off = 128; off > 0; off >>= 1) {
    if (t < off) red[t] += red[t+off];
    __syncthreads();
  }
  if (t == 0) bsum[blockIdx.x] = red[0];
}

// K3b: exclusive scan of block sums (single block)
__global__ __launch_bounds__(512) void scan_top(const int* __restrict__ bsum,
                                                int* __restrict__ boff) {
  __shared__ int sc[512];
  int t = threadIdx.x;
  int v = (t < SCAN_B) ? bsum[t] : 0;
  sc[t] = v;
  __syncthreads();
  for (int off = 1; off < 512; off <<= 1) {
    int add = (t >= off) ? sc[t-off] : 0;
    __syncthreads();
    sc[t] += add;
    __syncthreads();
  }
  if (t < SCAN_B) boff[t] = sc[t] - v;
}

// K3c: final exclusive scan -> start[]
__global__ __launch_bounds__(256) void scan_final(const int* __restrict__ deg,
    const int* __restrict__ boff, int* __restrict__ start) {
  __shared__ int sc[256];
  int t = threadIdx.x;
  int i4 = blockIdx.x*256 + t;
  int4 v = (i4 < NT4) ? ((const int4*)deg)[i4] : int4{0,0,0,0};
  int s01 = v.x + v.y;
  int sum = s01 + v.z + v.w;
  sc[t] = sum;
  __syncthreads();
  for (int off = 1; off < 256; off <<= 1) {
    int add = (t >= off) ? sc[t-off] : 0;
    __syncthreads();
    sc[t] += add;
    __syncthreads();
  }
  int excl = sc[t] - sum + boff[blockIdx.x];
  if (i4 < NT4) {
    int4 st;
    st.x = excl;
    st.y = excl + v.x;
    st.z = excl + s01;
    st.w = excl + s01 + v.z;
    ((int4*)start)[i4] = st;
  }
}

// K4: atomic-free scatter: slot = start[key] + precomputed rank.
//     One scattered store per thread; start[] gathers hit L2 (1.2 MB table).
__global__ __launch_bounds__(256) void scatter_kernel(K4 P,
    const int* __restrict__ start, int* __restrict__ src_sorted) {
  KRel R = P.r[blockIdx.y];
  int e = blockIdx.x*256 + threadIdx.x;
  if (e >= NEDGES) return;
  src_sorted[start[R.base + R.key[e]] + (int)R.rank[e]] = R.payload[e];
}

// K5: one wave per (dst node, relation): register-accumulated softmax-agg,
//     denominator + normalize + relu fused. Zero atomics. Src indices
//     prefetched 64-wide, broadcast via shfl; inner loop unrolled x4 with
//     independent accumulator pairs -> 8 gathers in flight per iteration.
//     Features gathered as fp16 (128B/row).
__global__ __launch_bounds__(256) void agg_kernel(ARels P,
    const int* __restrict__ csr_start, const int* __restrict__ deg,
    const int* __restrict__ src_sorted) {
  AggRel R = P.r[blockIdx.y];
  int lane = threadIdx.x & 63, wid = threadIdx.x >> 6;
  int n = blockIdx.x*4 + wid;
  if (n >= R.n_dst) return;
  int h = lane >> 3;
  float aldv = R.ald[(size_t)n*8 + h];
  int start = csr_start[R.base + n];
  int dcount = deg[R.base + n];
  float acc0 = 0.f, den0 = 0.f, acc1 = 0.f, den1 = 0.f;
  for (int j0 = 0; j0 < dcount; j0 += 64) {
    int idx = j0 + lane;
    int mysrc = (idx < dcount) ? src_sorted[start + idx] : 0;
    int cnt = dcount - j0; if (cnt > 64) cnt = 64;
    int jj = 0;
    for (; jj + 4 <= cnt; jj += 4) {
      int s0 = __shfl(mysrc, jj+0);
      int s1 = __shfl(mysrc, jj+1);
      int s2 = __shfl(mysrc, jj+2);
      int s3 = __shfl(mysrc, jj+3);
      float A0 = R.als[(size_t)s0*8 + h];
      float A1 = R.als[(size_t)s1*8 + h];
      float A2 = R.als[(size_t)s2*8 + h];
      float A3 = R.als[(size_t)s3*8 + h];
      float v0 = __half2float(R.hsrc[(size_t)s0*64 + lane]);
      float v1 = __half2float(R.hsrc[(size_t)s1*64 + lane]);
      float v2 = __half2float(R.hsrc[(size_t)s2*64 + lane]);
      float v3 = __half2float(R.hsrc[(size_t)s3*64 + lane]);
      A0 += aldv; A0 = A0 >= 0.f ? A0 : 0.2f*A0; float e0 = __expf(A0);
      A1 += aldv; A1 = A1 >= 0.f ? A1 : 0.2f*A1; float e1 = __expf(A1);
      A2 += aldv; A2 = A2 >= 0.f ? A2 : 0.2f*A2; float e2 = __expf(A2);
      A3 += aldv; A3 = A3 >= 0.f ? A3 : 0.2f*A3; float e3 = __expf(A3);
      den0 += e0 + e1; den1 += e2 + e3;
      acc0 = fmaf(e0, v0, acc0); acc1 = fmaf(e1, v1, acc1);
      acc0 = fmaf(e2, v2, acc0); acc1 = fmaf(e3, v3, acc1);
    }
    for (; jj < cnt; ++jj) {
      int s = __shfl(mysrc, jj);
      float a = R.als[(size_t)s*8 + h] + aldv;
      a = a >= 0.f ? a : 0.2f*a;
      float ex = __expf(a);    // no max-subtraction: softmax is shift-invariant
      den0 += ex;
      acc0 = fmaf(ex, __half2float(R.hsrc[(size_t)s*64 + lane]), acc0);
    }
  }
  float v = (acc0 + acc1) / (den0 + den1 + 1e-16f);
  R.outp[(size_t)n*64 + lane] = v > 0.f ? v : 0.f;
}

// K6: semacc[mp][c] += sum_n tanh( (O[n]@kw^T + kb)[c] )
//     Register-tiled: each thread computes 8 nodes for its channel — one
//     Kl[c][k] LDS read serves 8 FMAs (was 1:1). 32-node tiles, 4x fewer
//     barriers. tanh via hardware exp: tanh(y) = 1 - 2/(e^{2y}+1).
__global__ __launch_bounds__(256) void sem_stats_kernel(SemP P,
    const float* __restrict__ kw, const float* __restrict__ kb,
    float* __restrict__ semacc) {
  int mp = blockIdx.y;
  const float* O = P.p[mp]; int N = P.n[mp];
  __shared__ float Kl[64][65];   // +1 pad: conflict-free per-lane rows
  __shared__ float xl[32][64];
  __shared__ float red[4][64];
  int tid = threadIdx.x;
  for (int i = tid; i < 4096; i += 256) Kl[i>>6][i&63] = kw[i];
  int g = tid>>6, c = tid&63;    // wave g handles nodes [g*8, g*8+8) of the tile
  float kbc = kb[c];
  float accsum = 0.f;
  for (int nb = blockIdx.x*32; nb < N; nb += gridDim.x*32) {
    __syncthreads();             // xl reuse guard (covers Kl load on iter 0)
    #pragma unroll
    for (int t = 0; t < 8; ++t) {
      int i = tid + t*256;       // [0,2048): n=i>>6, k=i&63 — coalesced global read
      int node = nb + (i>>6);
      xl[i>>6][i&63] = (node < N) ? O[(size_t)node*64 + (i&63)] : 0.f;
    }
    __syncthreads();
    float acc[8] = {0.f,0.f,0.f,0.f,0.f,0.f,0.f,0.f};
    #pragma unroll
    for (int k = 0; k < 64; ++k) {
      float Kc = Kl[c][k];                       // 1 read : 8 FMAs
      #pragma unroll
      for (int j = 0; j < 8; ++j)
        acc[j] = fmaf(xl[g*8+j][k], Kc, acc[j]); // wave-uniform addr: broadcast
    }
    int rem = N - nb - g*8;
    #pragma unroll
    for (int j = 0; j < 8; ++j) {
      if (j < rem) {
        float e2 = __expf(2.f*(acc[j] + kbc));
        accsum += 1.f - 2.f/(e2 + 1.f);
      }
    }
  }
  red[g][c] = accsum;
  __syncthreads();
  if (tid < 64) {
    float tot = red[0][tid]+red[1][tid]+red[2][tid]+red[3][tid];
    atomicAdd(&semacc[mp*64+tid], tot);
  }
}

// K7: scores + 2x softmax(2) -> w[4]
__global__ void sem_weights_kernel(const float* __restrict__ semacc,
                                   const float* __restrict__ q,
                                   float* __restrict__ w) {
  int c = threadIdx.x; // 64 threads, one wave
  float qc = q[c];
  float sc[4];
  const float invN[4] = {1.f/NUSERS, 1.f/NUSERS, 1.f/NGAMES, 1.f/NGAMES};
  #pragma unroll
  for (int m = 0; m < 4; ++m) {
    float v = qc * semacc[m*64+c] * invN[m];
    #pragma unroll
    for (int mask = 1; mask < 64; mask <<= 1) v += __shfl_xor(v, mask);
    sc[m] = v;
  }
  if (c == 0) {
    float m0 = fmaxf(sc[0], sc[1]);
    float e0 = expf(sc[0]-m0), e1 = expf(sc[1]-m0);
    w[0] = e0/(e0+e1); w[1] = e1/(e0+e1);
    float m1 = fmaxf(sc[2], sc[3]);
    float e2 = expf(sc[2]-m1), e3 = expf(sc[3]-m1);
    w[2] = e2/(e2+e3); w[3] = e3/(e2+e3);
  }
}

// K8: out = w0*plays + w1*rec  (in place over d_out)
__global__ __launch_bounds__(256) void combine_kernel(
    float* __restrict__ out_u, const float* __restrict__ rec_u,
    float* __restrict__ out_g, const float* __restrict__ rec_g,
    const float* __restrict__ w) {
  int i = blockIdx.x*256 + threadIdx.x;
  if (blockIdx.y == 0) {
    if (i < NUSERS*64) out_u[i] = w[0]*out_u[i] + w[1]*rec_u[i];
  } else {
    if (i < NGAMES*64) out_g[i] = w[2]*out_g[i] + w[3]*rec_g[i];
  }
}

extern "C" void kernel_launch(void* const* d_in, const int* in_sizes, int n_in,
                              void* d_out_v, int out_size, void* d_ws, size_t ws_size,
                              hipStream_t stream) {
  const float* x_user     = (const float*)d_in[0];
  const float* x_game     = (const float*)d_in[1];
  const int*   plays_src  = (const int*)d_in[2];
  const int*   plays_dst  = (const int*)d_in[3];
  const int*   rec_src    = (const int*)d_in[4];
  const int*   rec_dst    = (const int*)d_in[5];
  const float* W_user     = (const float*)d_in[6];
  const float* b_user     = (const float*)d_in[7];
  const float* W_game     = (const float*)d_in[8];
  const float* b_game     = (const float*)d_in[9];
  const float* att_src_pg = (const float*)d_in[10];
  const float* att_dst_pg = (const float*)d_in[11];
  const float* att_src_rg = (const float*)d_in[12];
  const float* att_dst_rg = (const float*)d_in[13];
  const float* att_src_pu = (const float*)d_in[14];
  const float* att_dst_pu = (const float*)d_in[15];
  const float* att_src_ru = (const float*)d_in[16];
  const float* att_dst_ru = (const float*)d_in[17];
  const float* k_lin_w    = (const float*)d_in[18];
  const float* k_lin_b    = (const float*)d_in[19];
  const float* q          = (const float*)d_in[20];
  float* out = (float*)d_out_v;
  float* ws  = (float*)d_ws;

  // ---- workspace layout (~103 MB; 4-byte granular) ----
  size_t o = 0;
  __half* h_u16 = (__half*)(ws + o); o += (size_t)NUSERS*32;  // 100K x 64 halves
  __half* h_g16 = (__half*)(ws + o); o += (size_t)NGAMES*32;  //  50K x 64 halves
  float* alU0 = ws + o; o += (size_t)NUSERS*8;   // att_src_pg
  float* alU1 = ws + o; o += (size_t)NUSERS*8;   // att_src_rg
  float* alU2 = ws + o; o += (size_t)NUSERS*8;   // att_dst_pu
  float* alU3 = ws + o; o += (size_t)NUSERS*8;   // att_dst_ru
  float* alG0 = ws + o; o += (size_t)NGAMES*8;   // att_dst_pg
  float* alG1 = ws + o; o += (size_t)NGAMES*8;   // att_dst_rg
  float* alG2 = ws + o; o += (size_t)NGAMES*8;   // att_src_pu
  float* alG3 = ws + o; o += (size_t)NGAMES*8;   // att_src_ru
  float* acc1 = ws + o; o += (size_t)NGAMES*64;  // og_rec result
  float* acc3 = ws + o; o += (size_t)NUSERS*64;  // ou_rec result
  float* semacc = ws + o; o += 256;
  float* wbuf   = ws + o; o += 4;
  int* deg        = (int*)(ws + o); o += NT;       // degree counters (zeroed)
  int* csr_start  = (int*)(ws + o); o += NT;
  int* bsum       = (int*)(ws + o); o += 512;
  int* boff       = (int*)(ws + o); o += 512;
  unsigned short* rank_all = (unsigned short*)(ws + o); o += (size_t)2*NEDGES; // 4 rels x E ushort
  int* src_sorted = (int*)(ws + o); o += (size_t)4*NEDGES;

  float* out_u = out;                       // ou_plays result -> user region
  float* out_g = out + (size_t)NUSERS*64;   // og_plays result -> game region

  hipMemsetAsync(deg, 0, (size_t)NT*sizeof(int), stream);
  hipMemsetAsync(semacc, 0, 260*sizeof(float), stream);

  T2 TP;
  TP.t[0] = {x_user, W_user, b_user, att_src_pg, att_src_rg, att_dst_pu, att_dst_ru,
             h_u16, alU0, alU1, alU2, alU3, NUSERS};
  TP.t[1] = {x_game, W_game, b_game, att_dst_pg, att_dst_rg, att_src_pu, att_src_ru,
             h_g16, alG0, alG1, alG2, alG3, NGAMES};

  // counter-space bases: [0,NG)=og_plays  [NG,2NG)=og_rec
  //                      [2NG,2NG+NU)=ou_plays  [2NG+NU,NT)=ou_rec
  K4 KP;
  KP.r[0] = {plays_dst, plays_src, 0,               rank_all + 0*(size_t)NEDGES};
  KP.r[1] = {rec_dst,   rec_src,   NGAMES,          rank_all + 1*(size_t)NEDGES};
  KP.r[2] = {plays_src, plays_dst, 2*NGAMES,        rank_all + 2*(size_t)NEDGES};
  KP.r[3] = {rec_src,   rec_dst,   2*NGAMES+NUSERS, rank_all + 3*(size_t)NEDGES};

  trans_hist_kernel<<<dim3(TUB + TGB + 4*HB), 256, 0, stream>>>(TP, KP, deg);
  scan_blocksum<<<dim3(SCAN_B), 256, 0, stream>>>(deg, bsum);
  scan_top<<<dim3(1), 512, 0, stream>>>(bsum, boff);
  scan_final<<<dim3(SCAN_B), 256, 0, stream>>>(deg, boff, csr_start);
  scatter_kernel<<<dim3((NEDGES+255)/256, 4), 256, 0, stream>>>(KP, csr_start, src_sorted);

  ARels AP;
  AP.r[0] = {alU0, alG0, h_u16, out_g, 0,                 NGAMES};
  AP.r[1] = {alU1, alG1, h_u16, acc1,  NGAMES,            NGAMES};
  AP.r[2] = {alG2, alU2, h_g16, out_u, 2*NGAMES,          NUSERS};
  AP.r[3] = {alG3, alU3, h_g16, acc3,  2*NGAMES+NUSERS,   NUSERS};

  agg_kernel<<<dim3((NUSERS+3)/4, 4), 256, 0, stream>>>(AP, csr_start, deg, src_sorted);

  SemP S;
  S.p[0] = out_u; S.p[1] = acc3; S.p[2] = out_g; S.p[3] = acc1;
  S.n[0] = NUSERS; S.n[1] = NUSERS; S.n[2] = NGAMES; S.n[3] = NGAMES;
  sem_stats_kernel<<<dim3(512,4), 256, 0, stream>>>(S, k_lin_w, k_lin_b, semacc);
  sem_weights_kernel<<<1, 64, 0, stream>>>(semacc, q, wbuf);
  combine_kernel<<<dim3((NUSERS*64+255)/256, 2), 256, 0, stream>>>(out_u, acc3, out_g, acc1, wbuf);
}

// Round 12
// 665.835 us; speedup vs baseline: 1.4179x; 1.4179x over previous
//
#include <hip/hip_runtime.h>
#include <hip/hip_fp16.h>

#define NUSERS 100000
#define NGAMES 50000
#define NEDGES 1000000
#define NT     300000   // concatenated dst-counter space: 2*NGAMES + 2*NUSERS
#define NT4    75000    // NT/4
#define SCAN_B 293      // ceil(NT4/256)
#define TUB    3125     // ceil(NUSERS/32) transform user blocks
#define TGB    1563     // ceil(NGAMES/32) transform game blocks
#define HB     3907     // ceil(NEDGES/256) hist blocks per relation
// C=64, H=8, D=8, NEG_SLOPE=0.2

// One logical relation: key = node id the segment is grouped by,
// payload = node id stored into the segment. base = counter-space offset.
struct KRel { const int* key; const int* payload; int base; unsigned short* rank; };
struct K4 { KRel r[4]; };
struct AggRel { const float* als; const float* ald; const __half* hsrc;
                float* outp; int base; int n_dst; };
struct ARels { AggRel r[4]; };
struct SemP { const float* p[4]; int n[4]; };
struct TParm { const float* x; const float* W; const float* b;
               const float* att0; const float* att1; const float* att2; const float* att3;
               __half* hout; float* al0; float* al1; float* al2; float* al3; int N; };
struct T2 { TParm t[2]; };

// K1 (fused): grid-sliced kernel.
//  blocks [0, TUB+TGB): transform — h = x@W^T + b (fp16 out) + attention logits.
//  blocks [TUB+TGB, +4*HB): hist_rank — degree histogram whose atomicAdd return
//  value IS the edge's rank (stored coalesced, 2B/edge).
//  Transform is VALU/LDS-heavy, hist is transaction-bound with idle VALU —
//  fusing them lets transform ride along ~free (R11: fusion ~-30 µs, kept).
__global__ __launch_bounds__(256) void trans_hist_kernel(T2 TP, K4 KP,
                                                         int* __restrict__ deg) {
  int bid = blockIdx.x;
  if (bid < TUB + TGB) {
    TParm R = (bid < TUB) ? TP.t[0] : TP.t[1];
    int nb = (bid < TUB ? bid : bid - TUB) * 32;
    if (nb >= R.N) return;
    __shared__ float Wl[64][65];   // +1 pad: lanes read Wl[c][k] conflict-free
    __shared__ float xl[4][64];
    int tid = threadIdx.x;
    for (int i = tid; i < 4096; i += 256) Wl[i>>6][i&63] = R.W[i];
    int nl = tid>>6, c = tid&63;
    float bc  = R.b[c];
    float a0c = R.att0[c], a1c = R.att1[c], a2c = R.att2[c], a3c = R.att3[c];
    for (int pass = 0; pass < 8; ++pass) {
      int n = nb + pass*4 + nl;
      __syncthreads();                       // xl reuse guard (covers W load on pass 0)
      if (n < R.N) xl[nl][c] = R.x[(size_t)n*64 + c];
      __syncthreads();
      if (n >= R.N) continue;                // no syncs below — safe divergence
      float acc = bc;
      #pragma unroll
      for (int k = 0; k < 64; ++k) acc += xl[nl][k]*Wl[c][k];
      R.hout[(size_t)n*64+c] = __float2half(acc);
      float p0 = acc*a0c, p1 = acc*a1c, p2 = acc*a2c, p3 = acc*a3c;
      #pragma unroll
      for (int mask = 1; mask < 8; mask <<= 1) {  // reduce over d in each head's 8 lanes
        p0 += __shfl_xor(p0, mask);
        p1 += __shfl_xor(p1, mask);
        p2 += __shfl_xor(p2, mask);
        p3 += __shfl_xor(p3, mask);
      }
      int d = c&7, hh = c>>3;
      if      (d == 0) R.al0[n*8+hh] = p0;
      else if (d == 1) R.al1[n*8+hh] = p1;
      else if (d == 2) R.al2[n*8+hh] = p2;
      else if (d == 3) R.al3[n*8+hh] = p3;
    }
  } else {
    int hb  = bid - (TUB + TGB);
    int rel = hb / HB;
    int eb  = hb - rel*HB;
    KRel R = KP.r[rel];
    int e = eb*256 + threadIdx.x;
    if (e >= NEDGES) return;
    R.rank[e] = (unsigned short)atomicAdd(&deg[R.base + R.key[e]], 1);
  }
}

// K3a: per-block (1024-elem) sums
__global__ __launch_bounds__(256) void scan_blocksum(const int* __restrict__ deg,
                                                     int* __restrict__ bsum) {
  __shared__ int red[256];
  int t = threadIdx.x;
  int i4 = blockIdx.x*256 + t;
  int4 v = (i4 < NT4) ? ((const int4*)deg)[i4] : int4{0,0,0,0};
  red[t] = v.x+v.y+v.z+v.w;
  __syncthreads();
  for (int off = 128; off > 0; off >>= 1) {
    if (t < off) red[t] += red[t+off];
    __syncthreads();
  }
  if (t == 0) bsum[blockIdx.x] = red[0];
}

// K3b: exclusive scan of block sums (single block)
__global__ __launch_bounds__(512) void scan_top(const int* __restrict__ bsum,
                                                int* __restrict__ boff) {
  __shared__ int sc[512];
  int t = threadIdx.x;
  int v = (t < SCAN_B) ? bsum[t] : 0;
  sc[t] = v;
  __syncthreads();
  for (int off = 1; off < 512; off <<= 1) {
    int add = (t >= off) ? sc[t-off] : 0;
    __syncthreads();
    sc[t] += add;
    __syncthreads();
  }
  if (t < SCAN_B) boff[t] = sc[t] - v;
}

// K3c: final exclusive scan -> start[]
__global__ __launch_bounds__(256) void scan_final(const int* __restrict__ deg,
    const int* __restrict__ boff, int* __restrict__ start) {
  __shared__ int sc[256];
  int t = threadIdx.x;
  int i4 = blockIdx.x*256 + t;
  int4 v = (i4 < NT4) ? ((const int4*)deg)[i4] : int4{0,0,0,0};
  int s01 = v.x + v.y;
  int sum = s01 + v.z + v.w;
  sc[t] = sum;
  __syncthreads();
  for (int off = 1; off < 256; off <<= 1) {
    int add = (t >= off) ? sc[t-off] : 0;
    __syncthreads();
    sc[t] += add;
    __syncthreads();
  }
  int excl = sc[t] - sum + boff[blockIdx.x];
  if (i4 < NT4) {
    int4 st;
    st.x = excl;
    st.y = excl + v.x;
    st.z = excl + s01;
    st.w = excl + s01 + v.z;
    ((int4*)start)[i4] = st;
  }
}

// K4: atomic-free scatter: slot = start[key] + precomputed rank.
//     One scattered store per thread; start[] gathers hit L2 (1.2 MB table).
__global__ __launch_bounds__(256) void scatter_kernel(K4 P,
    const int* __restrict__ start, int* __restrict__ src_sorted) {
  KRel R = P.r[blockIdx.y];
  int e = blockIdx.x*256 + threadIdx.x;
  if (e >= NEDGES) return;
  src_sorted[start[R.base + R.key[e]] + (int)R.rank[e]] = R.payload[e];
}

// K5: one wave per (dst node, relation): register-accumulated softmax-agg,
//     denominator + normalize + relu fused. Zero atomics. Src indices
//     prefetched 64-wide, broadcast via shfl; inner loop unrolled x4 with
//     independent accumulator pairs -> 8 gathers in flight per iteration.
//     Features gathered as fp16 (128B/row).
__global__ __launch_bounds__(256) void agg_kernel(ARels P,
    const int* __restrict__ csr_start, const int* __restrict__ deg,
    const int* __restrict__ src_sorted) {
  AggRel R = P.r[blockIdx.y];
  int lane = threadIdx.x & 63, wid = threadIdx.x >> 6;
  int n = blockIdx.x*4 + wid;
  if (n >= R.n_dst) return;
  int h = lane >> 3;
  float aldv = R.ald[(size_t)n*8 + h];
  int start = csr_start[R.base + n];
  int dcount = deg[R.base + n];
  float acc0 = 0.f, den0 = 0.f, acc1 = 0.f, den1 = 0.f;
  for (int j0 = 0; j0 < dcount; j0 += 64) {
    int idx = j0 + lane;
    int mysrc = (idx < dcount) ? src_sorted[start + idx] : 0;
    int cnt = dcount - j0; if (cnt > 64) cnt = 64;
    int jj = 0;
    for (; jj + 4 <= cnt; jj += 4) {
      int s0 = __shfl(mysrc, jj+0);
      int s1 = __shfl(mysrc, jj+1);
      int s2 = __shfl(mysrc, jj+2);
      int s3 = __shfl(mysrc, jj+3);
      float A0 = R.als[(size_t)s0*8 + h];
      float A1 = R.als[(size_t)s1*8 + h];
      float A2 = R.als[(size_t)s2*8 + h];
      float A3 = R.als[(size_t)s3*8 + h];
      float v0 = __half2float(R.hsrc[(size_t)s0*64 + lane]);
      float v1 = __half2float(R.hsrc[(size_t)s1*64 + lane]);
      float v2 = __half2float(R.hsrc[(size_t)s2*64 + lane]);
      float v3 = __half2float(R.hsrc[(size_t)s3*64 + lane]);
      A0 += aldv; A0 = A0 >= 0.f ? A0 : 0.2f*A0; float e0 = __expf(A0);
      A1 += aldv; A1 = A1 >= 0.f ? A1 : 0.2f*A1; float e1 = __expf(A1);
      A2 += aldv; A2 = A2 >= 0.f ? A2 : 0.2f*A2; float e2 = __expf(A2);
      A3 += aldv; A3 = A3 >= 0.f ? A3 : 0.2f*A3; float e3 = __expf(A3);
      den0 += e0 + e1; den1 += e2 + e3;
      acc0 = fmaf(e0, v0, acc0); acc1 = fmaf(e1, v1, acc1);
      acc0 = fmaf(e2, v2, acc0); acc1 = fmaf(e3, v3, acc1);
    }
    for (; jj < cnt; ++jj) {
      int s = __shfl(mysrc, jj);
      float a = R.als[(size_t)s*8 + h] + aldv;
      a = a >= 0.f ? a : 0.2f*a;
      float ex = __expf(a);    // no max-subtraction: softmax is shift-invariant
      den0 += ex;
      acc0 = fmaf(ex, __half2float(R.hsrc[(size_t)s*64 + lane]), acc0);
    }
  }
  float v = (acc0 + acc1) / (den0 + den1 + 1e-16f);
  R.outp[(size_t)n*64 + lane] = v > 0.f ? v : 0.f;
}

// K6: semacc[mp][c] += sum_n tanh( (O[n]@kw^T + kb)[c] )
//     Moderate register tile (R11 post-mortem: 8-node tile spilled —
//     VGPR 256, 814 MB scratch writes): 4 nodes/thread in NAMED scalars,
//     16-node tiles, partial unroll to stop the compiler hoisting all 64
//     Kl reads. One Kl[c][k] read : 4 FMAs. tanh(y) = 1 - 2/(e^{2y}+1).
__global__ __launch_bounds__(256) void sem_stats_kernel(SemP P,
    const float* __restrict__ kw, const float* __restrict__ kb,
    float* __restrict__ semacc) {
  int mp = blockIdx.y;
  const float* O = P.p[mp]; int N = P.n[mp];
  __shared__ float Kl[64][65];   // +1 pad: conflict-free per-lane rows
  __shared__ float xl[16][64];
  __shared__ float red[4][64];
  int tid = threadIdx.x;
  for (int i = tid; i < 4096; i += 256) Kl[i>>6][i&63] = kw[i];
  int g = tid>>6, c = tid&63;    // wave g handles nodes [g*4, g*4+4) of the tile
  float kbc = kb[c];
  float accsum = 0.f;
  for (int nb = blockIdx.x*16; nb < N; nb += gridDim.x*16) {
    __syncthreads();             // xl reuse guard (covers Kl load on iter 0)
    #pragma unroll
    for (int t = 0; t < 4; ++t) {
      int i = tid + t*256;       // [0,1024): n=i>>6, k=i&63 — coalesced global read
      int node = nb + (i>>6);
      xl[i>>6][i&63] = (node < N) ? O[(size_t)node*64 + (i&63)] : 0.f;
    }
    __syncthreads();
    float a0 = 0.f, a1 = 0.f, a2 = 0.f, a3 = 0.f;   // named: no array scratch risk
    #pragma unroll 16            // partial: bounds register live ranges
    for (int k = 0; k < 64; ++k) {
      float Kc = Kl[c][k];                     // 1 per-lane read : 4 FMAs
      a0 = fmaf(xl[g*4+0][k], Kc, a0);         // wave-uniform addr: broadcast
      a1 = fmaf(xl[g*4+1][k], Kc, a1);
      a2 = fmaf(xl[g*4+2][k], Kc, a2);
      a3 = fmaf(xl[g*4+3][k], Kc, a3);
    }
    int rem = N - nb - g*4;
    if (0 < rem) { float e2 = __expf(2.f*(a0+kbc)); accsum += 1.f - 2.f/(e2+1.f); }
    if (1 < rem) { float e2 = __expf(2.f*(a1+kbc)); accsum += 1.f - 2.f/(e2+1.f); }
    if (2 < rem) { float e2 = __expf(2.f*(a2+kbc)); accsum += 1.f - 2.f/(e2+1.f); }
    if (3 < rem) { float e2 = __expf(2.f*(a3+kbc)); accsum += 1.f - 2.f/(e2+1.f); }
  }
  red[g][c] = accsum;
  __syncthreads();
  if (tid < 64) {
    float tot = red[0][tid]+red[1][tid]+red[2][tid]+red[3][tid];
    atomicAdd(&semacc[mp*64+tid], tot);
  }
}

// K7: scores + 2x softmax(2) -> w[4]
__global__ void sem_weights_kernel(const float* __restrict__ semacc,
                                   const float* __restrict__ q,
                                   float* __restrict__ w) {
  int c = threadIdx.x; // 64 threads, one wave
  float qc = q[c];
  float sc[4];
  const float invN[4] = {1.f/NUSERS, 1.f/NUSERS, 1.f/NGAMES, 1.f/NGAMES};
  #pragma unroll
  for (int m = 0; m < 4; ++m) {
    float v = qc * semacc[m*64+c] * invN[m];
    #pragma unroll
    for (int mask = 1; mask < 64; mask <<= 1) v += __shfl_xor(v, mask);
    sc[m] = v;
  }
  if (c == 0) {
    float m0 = fmaxf(sc[0], sc[1]);
    float e0 = expf(sc[0]-m0), e1 = expf(sc[1]-m0);
    w[0] = e0/(e0+e1); w[1] = e1/(e0+e1);
    float m1 = fmaxf(sc[2], sc[3]);
    float e2 = expf(sc[2]-m1), e3 = expf(sc[3]-m1);
    w[2] = e2/(e2+e3); w[3] = e3/(e2+e3);
  }
}

// K8: out = w0*plays + w1*rec  (in place over d_out)
__global__ __launch_bounds__(256) void combine_kernel(
    float* __restrict__ out_u, const float* __restrict__ rec_u,
    float* __restrict__ out_g, const float* __restrict__ rec_g,
    const float* __restrict__ w) {
  int i = blockIdx.x*256 + threadIdx.x;
  if (blockIdx.y == 0) {
    if (i < NUSERS*64) out_u[i] = w[0]*out_u[i] + w[1]*rec_u[i];
  } else {
    if (i < NGAMES*64) out_g[i] = w[2]*out_g[i] + w[3]*rec_g[i];
  }
}

extern "C" void kernel_launch(void* const* d_in, const int* in_sizes, int n_in,
                              void* d_out_v, int out_size, void* d_ws, size_t ws_size,
                              hipStream_t stream) {
  const float* x_user     = (const float*)d_in[0];
  const float* x_game     = (const float*)d_in[1];
  const int*   plays_src  = (const int*)d_in[2];
  const int*   plays_dst  = (const int*)d_in[3];
  const int*   rec_src    = (const int*)d_in[4];
  const int*   rec_dst    = (const int*)d_in[5];
  const float* W_user     = (const float*)d_in[6];
  const float* b_user     = (const float*)d_in[7];
  const float* W_game     = (const float*)d_in[8];
  const float* b_game     = (const float*)d_in[9];
  const float* att_src_pg = (const float*)d_in[10];
  const float* att_dst_pg = (const float*)d_in[11];
  const float* att_src_rg = (const float*)d_in[12];
  const float* att_dst_rg = (const float*)d_in[13];
  const float* att_src_pu = (const float*)d_in[14];
  const float* att_dst_pu = (const float*)d_in[15];
  const float* att_src_ru = (const float*)d_in[16];
  const float* att_dst_ru = (const float*)d_in[17];
  const float* k_lin_w    = (const float*)d_in[18];
  const float* k_lin_b    = (const float*)d_in[19];
  const float* q          = (const float*)d_in[20];
  float* out = (float*)d_out_v;
  float* ws  = (float*)d_ws;

  // ---- workspace layout (~103 MB; 4-byte granular) ----
  size_t o = 0;
  __half* h_u16 = (__half*)(ws + o); o += (size_t)NUSERS*32;  // 100K x 64 halves
  __half* h_g16 = (__half*)(ws + o); o += (size_t)NGAMES*32;  //  50K x 64 halves
  float* alU0 = ws + o; o += (size_t)NUSERS*8;   // att_src_pg
  float* alU1 = ws + o; o += (size_t)NUSERS*8;   // att_src_rg
  float* alU2 = ws + o; o += (size_t)NUSERS*8;   // att_dst_pu
  float* alU3 = ws + o; o += (size_t)NUSERS*8;   // att_dst_ru
  float* alG0 = ws + o; o += (size_t)NGAMES*8;   // att_dst_pg
  float* alG1 = ws + o; o += (size_t)NGAMES*8;   // att_dst_rg
  float* alG2 = ws + o; o += (size_t)NGAMES*8;   // att_src_pu
  float* alG3 = ws + o; o += (size_t)NGAMES*8;   // att_src_ru
  float* acc1 = ws + o; o += (size_t)NGAMES*64;  // og_rec result
  float* acc3 = ws + o; o += (size_t)NUSERS*64;  // ou_rec result
  float* semacc = ws + o; o += 256;
  float* wbuf   = ws + o; o += 4;
  int* deg        = (int*)(ws + o); o += NT;       // degree counters (zeroed)
  int* csr_start  = (int*)(ws + o); o += NT;
  int* bsum       = (int*)(ws + o); o += 512;
  int* boff       = (int*)(ws + o); o += 512;
  unsigned short* rank_all = (unsigned short*)(ws + o); o += (size_t)2*NEDGES; // 4 rels x E ushort
  int* src_sorted = (int*)(ws + o); o += (size_t)4*NEDGES;

  float* out_u = out;                       // ou_plays result -> user region
  float* out_g = out + (size_t)NUSERS*64;   // og_plays result -> game region

  hipMemsetAsync(deg, 0, (size_t)NT*sizeof(int), stream);
  hipMemsetAsync(semacc, 0, 260*sizeof(float), stream);

  T2 TP;
  TP.t[0] = {x_user, W_user, b_user, att_src_pg, att_src_rg, att_dst_pu, att_dst_ru,
             h_u16, alU0, alU1, alU2, alU3, NUSERS};
  TP.t[1] = {x_game, W_game, b_game, att_dst_pg, att_dst_rg, att_src_pu, att_src_ru,
             h_g16, alG0, alG1, alG2, alG3, NGAMES};

  // counter-space bases: [0,NG)=og_plays  [NG,2NG)=og_rec
  //                      [2NG,2NG+NU)=ou_plays  [2NG+NU,NT)=ou_rec
  K4 KP;
  KP.r[0] = {plays_dst, plays_src, 0,               rank_all + 0*(size_t)NEDGES};
  KP.r[1] = {rec_dst,   rec_src,   NGAMES,          rank_all + 1*(size_t)NEDGES};
  KP.r[2] = {plays_src, plays_dst, 2*NGAMES,        rank_all + 2*(size_t)NEDGES};
  KP.r[3] = {rec_src,   rec_dst,   2*NGAMES+NUSERS, rank_all + 3*(size_t)NEDGES};

  trans_hist_kernel<<<dim3(TUB + TGB + 4*HB), 256, 0, stream>>>(TP, KP, deg);
  scan_blocksum<<<dim3(SCAN_B), 256, 0, stream>>>(deg, bsum);
  scan_top<<<dim3(1), 512, 0, stream>>>(bsum, boff);
  scan_final<<<dim3(SCAN_B), 256, 0, stream>>>(deg, boff, csr_start);
  scatter_kernel<<<dim3((NEDGES+255)/256, 4), 256, 0, stream>>>(KP, csr_start, src_sorted);

  ARels AP;
  AP.r[0] = {alU0, alG0, h_u16, out_g, 0,                 NGAMES};
  AP.r[1] = {alU1, alG1, h_u16, acc1,  NGAMES,            NGAMES};
  AP.r[2] = {alG2, alU2, h_g16, out_u, 2*NGAMES,          NUSERS};
  AP.r[3] = {alG3, alU3, h_g16, acc3,  2*NGAMES+NUSERS,   NUSERS};

  agg_kernel<<<dim3((NUSERS+3)/4, 4), 256, 0, stream>>>(AP, csr_start, deg, src_sorted);

  SemP S;
  S.p[0] = out_u; S.p[1] = acc3; S.p[2] = out_g; S.p[3] = acc1;
  S.n[0] = NUSERS; S.n[1] = NUSERS; S.n[2] = NGAMES; S.n[3] = NGAMES;
  sem_stats_kernel<<<dim3(512,4), 256, 0, stream>>>(S, k_lin_w, k_lin_b, semacc);
  sem_weights_kernel<<<1, 64, 0, stream>>>(semacc, q, wbuf);
  combine_kernel<<<dim3((NUSERS*64+255)/256, 2), 256, 0, stream>>>(out_u, acc3, out_g, acc1, wbuf);
}